// Round 1
// baseline (393.496 us; speedup 1.0000x reference)
//
#include <hip/hip_runtime.h>
#include <stdint.h>

typedef unsigned short u16;
typedef short bf16x8 __attribute__((ext_vector_type(8)));   // 8 bf16 in 4 VGPRs (guide §3)
typedef float f32x4 __attribute__((ext_vector_type(4)));

typedef void as1_void __attribute__((address_space(1)));
typedef void as3_void __attribute__((address_space(3)));

__device__ inline u16 f32_to_bf16(float f) {
    uint32_t u = __builtin_bit_cast(uint32_t, f);
    u += 0x7fffu + ((u >> 16) & 1u);   // round-to-nearest-even (finite values only)
    return (u16)(u >> 16);
}

__device__ inline void gld_lds16(const void* g, void* l) {
    // async global->LDS, 16B/lane; LDS dest is wave-uniform base + lane*16
    __builtin_amdgcn_global_load_lds((as1_void*)g, (as3_void*)l, 16, 0, 0);
}

// ---------------- prep kernels ----------------

__global__ void prep_w_kernel(const float* __restrict__ v_log,
                              const float* __restrict__ theta_log,
                              float* __restrict__ wfull, int H) {
    int h = blockIdx.x * blockDim.x + threadIdx.x;
    if (h < H) {
        float mag = expf(-expf(v_log[h]));
        float ang = expf(theta_log[h]);
        wfull[h]     = mag * cosf(ang);
        wfull[h + H] = mag * sinf(ang);
    }
}

__global__ void cast_f32_bf16_kernel(const float* __restrict__ src,
                                     u16* __restrict__ dst, int n4) {
    int i = blockIdx.x * blockDim.x + threadIdx.x;
    if (i < n4) {
        float4 f = ((const float4*)src)[i];
        ushort4 o;
        o.x = f32_to_bf16(f.x);
        o.y = f32_to_bf16(f.y);
        o.z = f32_to_bf16(f.z);
        o.w = f32_to_bf16(f.w);
        ((ushort4*)dst)[i] = o;
    }
}

// W2[o][k] = Cr[o][k] for k<2048, -Ci[o][k-2048] for k>=2048   (row-major [1024][4096])
__global__ void pack_w2_kernel(const float* __restrict__ Cr,
                               const float* __restrict__ Ci,
                               u16* __restrict__ W2, int total4) {
    int i = blockIdx.x * blockDim.x + threadIdx.x;
    if (i >= total4) return;
    int e = i * 4;
    int o = e >> 12;       // / 4096
    int k = e & 4095;
    float4 f; float s;
    if (k < 2048) { f = *(const float4*)(Cr + (size_t)o * 2048 + k);        s =  1.f; }
    else          { f = *(const float4*)(Ci + (size_t)o * 2048 + (k-2048)); s = -1.f; }
    ushort4 u;
    u.x = f32_to_bf16(s * f.x);
    u.y = f32_to_bf16(s * f.y);
    u.z = f32_to_bf16(s * f.z);
    u.w = f32_to_bf16(s * f.w);
    ((ushort4*)W2)[i] = u;
}

// ---------------- GEMM: C[M,N] = A[M,K] * B[N,K]^T (both bf16 row-major) ----------------
// m97 structure: 128x128 tile, BK=32, 4 waves 2x2, each wave 4x4 of 16x16x32 MFMA.
// EPI==1: C += h_prev[row, col&2047]*wfull[col], store bf16. EPI==0: store f32.

template<int EPI>
__global__ __launch_bounds__(256)
void gemm_bt_kernel(const u16* __restrict__ A, const u16* __restrict__ B,
                    int M, int N, int K,
                    const float* __restrict__ h_prev,
                    const float* __restrict__ wfull,
                    u16* __restrict__ outBf,
                    float* __restrict__ outF)
{
    __shared__ __align__(16) u16 ldsA[128 * 32];   // contiguous: required by global_load_lds
    __shared__ __align__(16) u16 ldsB[128 * 32];

    const int tid  = threadIdx.x;
    const int wid  = tid >> 6;
    const int lane = tid & 63;
    const int quad = lane >> 4;
    const int l16  = lane & 15;
    const int wave_m = wid >> 1;
    const int wave_n = wid & 1;

    const int bm = blockIdx.y;
    const int bn = blockIdx.x;

    // staging: 512 chunks of 16B per tile; wave w covers chunks w*128 + j*64 + lane
    const int chunk0 = wid * 128 + lane;
    const int chunk1 = chunk0 + 64;
    const int rA0 = chunk0 >> 2, cA0 = (chunk0 & 3) * 8;
    const int rA1 = chunk1 >> 2, cA1 = (chunk1 & 3) * 8;

    const u16* Ab = A + (size_t)(bm * 128) * K;
    const u16* Bb = B + (size_t)(bn * 128) * K;
    const u16* gA0 = Ab + (size_t)rA0 * K + cA0;
    const u16* gA1 = Ab + (size_t)rA1 * K + cA1;
    const u16* gB0 = Bb + (size_t)rA0 * K + cA0;
    const u16* gB1 = Bb + (size_t)rA1 * K + cA1;

    u16* lA0 = ldsA + chunk0 * 8;
    u16* lA1 = ldsA + chunk1 * 8;
    u16* lB0 = ldsB + chunk0 * 8;
    u16* lB1 = ldsB + chunk1 * 8;

    const f32x4 fzero = {0.f, 0.f, 0.f, 0.f};
    f32x4 acc[4][4];
#pragma unroll
    for (int i = 0; i < 4; i++)
#pragma unroll
        for (int j = 0; j < 4; j++)
            acc[i][j] = fzero;

    for (int k0 = 0; k0 < K; k0 += 32) {
        __syncthreads();                 // previous iter's ds_reads done before overwrite
        gld_lds16(gA0 + k0, lA0);
        gld_lds16(gA1 + k0, lA1);
        gld_lds16(gB0 + k0, lB0);
        gld_lds16(gB1 + k0, lB1);
        __syncthreads();                 // implies s_waitcnt vmcnt(0): staged data visible

        bf16x8 af[4], bfr[4];
#pragma unroll
        for (int i = 0; i < 4; i++) {
            int row = wave_m * 64 + i * 16 + l16;         // A[m][k]: m=lane&15, k=quad*8+j
            af[i] = *(const bf16x8*)(ldsA + row * 32 + quad * 8);
        }
#pragma unroll
        for (int j = 0; j < 4; j++) {
            int row = wave_n * 64 + j * 16 + l16;
            bfr[j] = *(const bf16x8*)(ldsB + row * 32 + quad * 8);
        }
#pragma unroll
        for (int i = 0; i < 4; i++)
#pragma unroll
            for (int j = 0; j < 4; j++)
                acc[i][j] = __builtin_amdgcn_mfma_f32_16x16x32_bf16(af[i], bfr[j], acc[i][j], 0, 0, 0);
    }

    // C/D layout: col = lane&15, row = quad*4 + reg  (guide §3, m89-verified)
    const int gm = bm * 128 + wave_m * 64;
    const int gn = bn * 128 + wave_n * 64;
#pragma unroll
    for (int i = 0; i < 4; i++) {
#pragma unroll
        for (int j = 0; j < 4; j++) {
            int col = gn + j * 16 + l16;
#pragma unroll
            for (int r = 0; r < 4; r++) {
                int row = gm + i * 16 + quad * 4 + r;
                float v = acc[i][j][r];
                if (EPI == 1) {
                    v += h_prev[(size_t)row * 2048 + (col & 2047)] * wfull[col];
                    outBf[(size_t)row * N + col] = f32_to_bf16(v);
                } else {
                    outF[(size_t)row * N + col] = v;
                }
            }
        }
    }
}

// ---------------- launch ----------------

extern "C" void kernel_launch(void* const* d_in, const int* in_sizes, int n_in,
                              void* d_out, int out_size, void* d_ws, size_t ws_size,
                              hipStream_t stream)
{
    const float* x      = (const float*)d_in[0];
    const float* h_prev = (const float*)d_in[1];
    const float* Br     = (const float*)d_in[2];
    const float* Bi     = (const float*)d_in[3];
    const float* Cr     = (const float*)d_in[4];
    const float* Ci     = (const float*)d_in[5];
    const float* v_log  = (const float*)d_in[6];
    const float* th_log = (const float*)d_in[7];
    float* out = (float*)d_out;

    const int Bsz = 8192, IN = 1024, H = 2048, OUT = 1024;
    const int N1 = 2 * H;    // 4096

    // workspace layout (~96.8 MB)
    size_t need = (size_t)Bsz*IN*2 + (size_t)N1*IN*2 + (size_t)OUT*N1*2
                + (size_t)Bsz*N1*2 + (size_t)N1*4;
    if (ws_size < need) return;   // fail loudly rather than corrupt memory

    char* ws = (char*)d_ws;
    u16*   x_bf  = (u16*)ws;   ws += (size_t)Bsz * IN * 2;   // 16 MB
    u16*   W1    = (u16*)ws;   ws += (size_t)N1 * IN * 2;    //  8 MB
    u16*   W2    = (u16*)ws;   ws += (size_t)OUT * N1 * 2;   //  8 MB
    u16*   H12   = (u16*)ws;   ws += (size_t)Bsz * N1 * 2;   // 64 MB
    float* wfull = (float*)ws;

    prep_w_kernel<<<(H + 255) / 256, 256, 0, stream>>>(v_log, th_log, wfull, H);
    cast_f32_bf16_kernel<<<(Bsz * IN / 4) / 256, 256, 0, stream>>>(x, x_bf, Bsz * IN / 4);
    cast_f32_bf16_kernel<<<(H * IN / 4) / 256, 256, 0, stream>>>(Br, W1, H * IN / 4);
    cast_f32_bf16_kernel<<<(H * IN / 4) / 256, 256, 0, stream>>>(Bi, W1 + (size_t)H * IN, H * IN / 4);
    pack_w2_kernel<<<(OUT * N1 / 4) / 256, 256, 0, stream>>>(Cr, Ci, W2, OUT * N1 / 4);

    dim3 blk(256);
    dim3 g1(N1 / 128, Bsz / 128);   // 32 x 64
    gemm_bt_kernel<1><<<g1, blk, 0, stream>>>(x_bf, W1, Bsz, N1, IN, h_prev, wfull, H12, nullptr);

    dim3 g2(OUT / 128, Bsz / 128);  // 8 x 64
    gemm_bt_kernel<0><<<g2, blk, 0, stream>>>(H12, W2, Bsz, OUT, N1, nullptr, nullptr, nullptr, out);
}

// Round 2
// 298.309 us; speedup vs baseline: 1.3191x; 1.3191x over previous
//
#include <hip/hip_runtime.h>
#include <stdint.h>

typedef unsigned short u16;
typedef short bf16x8 __attribute__((ext_vector_type(8)));   // 8 bf16 in 4 VGPRs
typedef float f32x4 __attribute__((ext_vector_type(4)));

typedef void as1_void __attribute__((address_space(1)));
typedef void as3_void __attribute__((address_space(3)));

__device__ inline u16 f32_to_bf16(float f) {
    uint32_t u = __builtin_bit_cast(uint32_t, f);
    u += 0x7fffu + ((u >> 16) & 1u);   // RNE (finite values only)
    return (u16)(u >> 16);
}

__device__ inline void gld_lds16(const void* g, void* l) {
    // async global->LDS, 16B/lane; HW dest = wave-uniform base + lane*16
    __builtin_amdgcn_global_load_lds((as1_void*)g, (as3_void*)l, 16, 0, 0);
}

// ---------------- small prep kernels ----------------

__global__ void prep_w_kernel(const float* __restrict__ v_log,
                              const float* __restrict__ theta_log,
                              float* __restrict__ wfull, int H) {
    int h = blockIdx.x * blockDim.x + threadIdx.x;
    if (h < H) {
        float mag = expf(-expf(v_log[h]));
        float ang = expf(theta_log[h]);
        wfull[h]     = mag * cosf(ang);
        wfull[h + H] = mag * sinf(ang);
    }
}

// Ccat[o][k] = Cr[o][k] (k<2048), -Ci[o][k-2048] (k>=2048); row-major [1024][4096] bf16
__global__ void pack_ccat_kernel(const float* __restrict__ Cr,
                                 const float* __restrict__ Ci,
                                 u16* __restrict__ Ccat, int total4) {
    int i = blockIdx.x * blockDim.x + threadIdx.x;
    if (i >= total4) return;
    int e = i * 4;
    int o = e >> 12;
    int k = e & 4095;
    float4 f; float s;
    if (k < 2048) { f = *(const float4*)(Cr + (size_t)o * 2048 + k);          s =  1.f; }
    else          { f = *(const float4*)(Ci + (size_t)o * 2048 + (k - 2048)); s = -1.f; }
    ushort4 u;
    u.x = f32_to_bf16(s * f.x); u.y = f32_to_bf16(s * f.y);
    u.z = f32_to_bf16(s * f.z); u.w = f32_to_bf16(s * f.w);
    ((ushort4*)Ccat)[i] = u;
}

// dst[c * dstStride + colOff + r] = bf16(src[r * C + c])  — 32x32 LDS tile transpose
__global__ void transpose_cast_kernel(const float* __restrict__ src, int R, int C,
                                      u16* __restrict__ dst, int dstStride, int colOff) {
    __shared__ float t[32][33];
    int c0 = blockIdx.x * 32, r0 = blockIdx.y * 32;
    int tx = threadIdx.x, ty = threadIdx.y;   // 32 x 8
#pragma unroll
    for (int j = 0; j < 4; j++)
        t[ty + j * 8][tx] = src[(size_t)(r0 + ty + j * 8) * C + c0 + tx];
    __syncthreads();
#pragma unroll
    for (int j = 0; j < 4; j++)
        dst[(size_t)(c0 + ty + j * 8) * dstStride + colOff + r0 + tx] =
            f32_to_bf16(t[tx][ty + j * 8]);
}

// strided cast: src f32 [rows, cols] -> dst bf16 at [row, colOff + col], row stride dstStride
__global__ void cast_into_kernel(const float* __restrict__ src, u16* __restrict__ dst,
                                 int cols4, int dstStride, int colOff, int n4) {
    int i = blockIdx.x * blockDim.x + threadIdx.x;
    if (i >= n4) return;
    int r = i / cols4;
    int c = (i - r * cols4) * 4;
    float4 f = ((const float4*)src)[i];
    ushort4 u;
    u.x = f32_to_bf16(f.x); u.y = f32_to_bf16(f.y);
    u.z = f32_to_bf16(f.z); u.w = f32_to_bf16(f.w);
    *(ushort4*)(dst + (size_t)r * dstStride + colOff + c) = u;
}

// Wcat[o][1024 + h] = bf16(Cr[o][h]*wr[h] - Ci[o][h]*wi[h])
__global__ void cw_kernel(const float* __restrict__ Cr, const float* __restrict__ Ci,
                          const float* __restrict__ wfull, u16* __restrict__ Wcat, int n4) {
    int i = blockIdx.x * blockDim.x + threadIdx.x;
    if (i >= n4) return;
    int o = i >> 9;               // /512 (2048 cols / 4)
    int h = (i & 511) * 4;
    float4 cr = *(const float4*)(Cr + (size_t)o * 2048 + h);
    float4 ci = *(const float4*)(Ci + (size_t)o * 2048 + h);
    float4 wr = *(const float4*)(wfull + h);
    float4 wi = *(const float4*)(wfull + 2048 + h);
    ushort4 u;
    u.x = f32_to_bf16(cr.x * wr.x - ci.x * wi.x);
    u.y = f32_to_bf16(cr.y * wr.y - ci.y * wi.y);
    u.z = f32_to_bf16(cr.z * wr.z - ci.z * wi.z);
    u.w = f32_to_bf16(cr.w * wr.w - ci.w * wi.w);
    *(ushort4*)(Wcat + (size_t)o * 3072 + 1024 + h) = u;
}

// partial reduce: Wcat[o][i] = bf16(sum_z partials[z][o][i])
__global__ void reduce_w_kernel(const float* __restrict__ partials, u16* __restrict__ Wcat, int n4) {
    int i = blockIdx.x * blockDim.x + threadIdx.x;
    if (i >= n4) return;
    int e = i * 4;
    float4 s = *(const float4*)(partials + e);
#pragma unroll
    for (int z = 1; z < 8; z++) {
        float4 p = *(const float4*)(partials + ((size_t)z << 20) + e);
        s.x += p.x; s.y += p.y; s.z += p.z; s.w += p.w;
    }
    int o = e >> 10;
    int c = e & 1023;
    ushort4 u;
    u.x = f32_to_bf16(s.x); u.y = f32_to_bf16(s.y);
    u.z = f32_to_bf16(s.z); u.w = f32_to_bf16(s.w);
    *(ushort4*)(Wcat + (size_t)o * 3072 + c) = u;
}

// ---------------- weight GEMM: split-K, 128x128 tile ----------------
// partials[bz][m][n] = sum_{k in chunk bz} Ccat[m][k] * Bcat[n][k], K=4096, chunk=512

__global__ __launch_bounds__(256)
void gemm_splitk_kernel(const u16* __restrict__ A, const u16* __restrict__ B,
                        float* __restrict__ partials)
{
    __shared__ __align__(16) u16 ldsA[128 * 32];
    __shared__ __align__(16) u16 ldsB[128 * 32];
    const int K = 4096;

    const int tid = threadIdx.x, wid = tid >> 6, lane = tid & 63;
    const int quad = lane >> 4, l16 = lane & 15;
    const int wm = wid >> 1, wn = wid & 1;
    const int bm = blockIdx.y, bn = blockIdx.x, bz = blockIdx.z;
    const int kb = bz * 512;

    const int c0 = wid * 128 + lane, c1 = c0 + 64;
    const int r0 = c0 >> 2, o0 = (c0 & 3) * 8;
    const int r1 = c1 >> 2, o1 = (c1 & 3) * 8;

    const u16* gA0 = A + (size_t)(bm * 128 + r0) * K + o0 + kb;
    const u16* gA1 = A + (size_t)(bm * 128 + r1) * K + o1 + kb;
    const u16* gB0 = B + (size_t)(bn * 128 + r0) * K + o0 + kb;
    const u16* gB1 = B + (size_t)(bn * 128 + r1) * K + o1 + kb;
    u16* lA0 = ldsA + c0 * 8; u16* lA1 = ldsA + c1 * 8;
    u16* lB0 = ldsB + c0 * 8; u16* lB1 = ldsB + c1 * 8;

    const f32x4 fz = {0.f, 0.f, 0.f, 0.f};
    f32x4 acc[4][4];
#pragma unroll
    for (int i = 0; i < 4; i++)
#pragma unroll
        for (int j = 0; j < 4; j++) acc[i][j] = fz;

    for (int k0 = 0; k0 < 512; k0 += 32) {
        __syncthreads();
        gld_lds16(gA0 + k0, lA0);
        gld_lds16(gA1 + k0, lA1);
        gld_lds16(gB0 + k0, lB0);
        gld_lds16(gB1 + k0, lB1);
        __syncthreads();
        bf16x8 af[4], bfr[4];
#pragma unroll
        for (int i = 0; i < 4; i++)
            af[i] = *(const bf16x8*)(ldsA + (wm * 64 + i * 16 + l16) * 32 + quad * 8);
#pragma unroll
        for (int j = 0; j < 4; j++)
            bfr[j] = *(const bf16x8*)(ldsB + (wn * 64 + j * 16 + l16) * 32 + quad * 8);
#pragma unroll
        for (int i = 0; i < 4; i++)
#pragma unroll
            for (int j = 0; j < 4; j++)
                acc[i][j] = __builtin_amdgcn_mfma_f32_16x16x32_bf16(af[i], bfr[j], acc[i][j], 0, 0, 0);
    }

    float* P = partials + ((size_t)bz << 20);
    const int gm = bm * 128 + wm * 64, gn = bn * 128 + wn * 64;
#pragma unroll
    for (int i = 0; i < 4; i++)
#pragma unroll
        for (int j = 0; j < 4; j++) {
            int col = gn + j * 16 + l16;
#pragma unroll
            for (int r = 0; r < 4; r++) {
                int row = gm + i * 16 + quad * 4 + r;
                P[(size_t)row * 1024 + col] = acc[i][j][r];
            }
        }
}

// ---------------- main GEMM: out[8192,1024] = Acat[8192,3072] @ Wcat[1024,3072]^T ----------------
// tile 128M x 64N, BK=32 -> grid (16, 64) = 1024 blocks (4/CU)

__global__ __launch_bounds__(256)
void gemm_main_kernel(const u16* __restrict__ A, const u16* __restrict__ B,
                      float* __restrict__ out)
{
    __shared__ __align__(16) u16 lds[768 * 8];   // chunks 0..511 = A-tile, 512..767 = B-tile
    const int LDK = 3072;

    const int tid = threadIdx.x, wid = tid >> 6, lane = tid & 63;
    const int quad = lane >> 4, l16 = lane & 15;
    const int wm = wid >> 1, wn = wid & 1;
    const int bm = blockIdx.y, bn = blockIdx.x;

    const u16* Ab = A + (size_t)(bm * 128) * LDK;
    const u16* Bb = B + (size_t)(bn * 64) * LDK;

    const u16* gsrc[3];
    u16* ldst[3];
#pragma unroll
    for (int j = 0; j < 3; j++) {
        int c = wid * 192 + j * 64 + lane;   // each 64-chunk issue is LDS-contiguous, single matrix
        ldst[j] = lds + c * 8;
        if (c < 512) gsrc[j] = Ab + (size_t)(c >> 2) * LDK + (c & 3) * 8;
        else { int c2 = c - 512; gsrc[j] = Bb + (size_t)(c2 >> 2) * LDK + (c2 & 3) * 8; }
    }

    const u16* ldsA = lds;
    const u16* ldsB = lds + 512 * 8;

    const f32x4 fz = {0.f, 0.f, 0.f, 0.f};
    f32x4 acc[4][2];
#pragma unroll
    for (int i = 0; i < 4; i++) { acc[i][0] = fz; acc[i][1] = fz; }

    for (int k0 = 0; k0 < 3072; k0 += 32) {
        __syncthreads();
        gld_lds16(gsrc[0] + k0, ldst[0]);
        gld_lds16(gsrc[1] + k0, ldst[1]);
        gld_lds16(gsrc[2] + k0, ldst[2]);
        __syncthreads();
        bf16x8 af[4], bfr[2];
#pragma unroll
        for (int i = 0; i < 4; i++)
            af[i] = *(const bf16x8*)(ldsA + (wm * 64 + i * 16 + l16) * 32 + quad * 8);
#pragma unroll
        for (int j = 0; j < 2; j++)
            bfr[j] = *(const bf16x8*)(ldsB + (wn * 32 + j * 16 + l16) * 32 + quad * 8);
#pragma unroll
        for (int i = 0; i < 4; i++)
#pragma unroll
            for (int j = 0; j < 2; j++)
                acc[i][j] = __builtin_amdgcn_mfma_f32_16x16x32_bf16(af[i], bfr[j], acc[i][j], 0, 0, 0);
    }

    const int gm = bm * 128 + wm * 64, gn = bn * 64 + wn * 32;
#pragma unroll
    for (int i = 0; i < 4; i++)
#pragma unroll
        for (int j = 0; j < 2; j++) {
            int col = gn + j * 16 + l16;
#pragma unroll
            for (int r = 0; r < 4; r++) {
                int row = gm + i * 16 + quad * 4 + r;
                out[(size_t)row * 1024 + col] = acc[i][j][r];
            }
        }
}

// ---------------- launch ----------------

extern "C" void kernel_launch(void* const* d_in, const int* in_sizes, int n_in,
                              void* d_out, int out_size, void* d_ws, size_t ws_size,
                              hipStream_t stream)
{
    const float* x      = (const float*)d_in[0];
    const float* h_prev = (const float*)d_in[1];
    const float* Br     = (const float*)d_in[2];
    const float* Bi     = (const float*)d_in[3];
    const float* Cr     = (const float*)d_in[4];
    const float* Ci     = (const float*)d_in[5];
    const float* v_log  = (const float*)d_in[6];
    const float* th_log = (const float*)d_in[7];
    float* out = (float*)d_out;

    const int H = 2048;
    const size_t MB = 1024 * 1024;

    // ws layout (54.02 MB): region0 (48 MB) holds {Ccat 8 | Bcat 8 | partials 32} during
    // weight prep, then is reused as Acat (48 MB). Wcat (6 MB) + wfull after it.
    size_t need = 48 * MB + (size_t)1024 * 3072 * 2 + 4096 * 4;
    if (ws_size < need) return;

    char* ws = (char*)d_ws;
    u16*   Ccat     = (u16*)ws;                       // [1024,4096] bf16
    u16*   Bcat     = (u16*)(ws + 8 * MB);            // [1024,4096] bf16 = [BrT|BiT]
    float* partials = (float*)(ws + 16 * MB);         // [8][1024][1024] f32
    u16*   Acat     = (u16*)ws;                       // [8192,3072] bf16 (aliases the above)
    u16*   Wcat     = (u16*)(ws + 48 * MB);           // [1024,3072] bf16 = [W|Cw]
    float* wfull    = (float*)(ws + 48 * MB + (size_t)1024 * 3072 * 2);

    // 1) diagonal weights
    prep_w_kernel<<<8, 256, 0, stream>>>(v_log, th_log, wfull, H);
    // 2) Ccat = [Cr | -Ci]
    pack_ccat_kernel<<<4096, 256, 0, stream>>>(Cr, Ci, Ccat, 1024 * 4096 / 4);
    // 3) Bcat = [Br^T | Bi^T]
    transpose_cast_kernel<<<dim3(32, 64), dim3(32, 8), 0, stream>>>(Br, 2048, 1024, Bcat, 4096, 0);
    transpose_cast_kernel<<<dim3(32, 64), dim3(32, 8), 0, stream>>>(Bi, 2048, 1024, Bcat, 4096, 2048);
    // 4) W partials = Ccat @ Bcat^T (split-K=8)
    gemm_splitk_kernel<<<dim3(8, 8, 8), 256, 0, stream>>>(Ccat, Bcat, partials);
    // 5) Wcat[:, 0:1024] = bf16(sum partials)
    reduce_w_kernel<<<1024, 256, 0, stream>>>(partials, Wcat, 1024 * 1024 / 4);
    // 6) Wcat[:, 1024:3072] = Cr*wr - Ci*wi
    cw_kernel<<<2048, 256, 0, stream>>>(Cr, Ci, wfull, Wcat, 1024 * 2048 / 4);
    // 7) Acat = [x | h_prev] bf16  (overwrites prep buffers — they're consumed)
    cast_into_kernel<<<8192, 256, 0, stream>>>(x, Acat, 256, 3072, 0, 8192 * 1024 / 4);
    cast_into_kernel<<<16384, 256, 0, stream>>>(h_prev, Acat, 512, 3072, 1024, 8192 * 2048 / 4);
    // 8) out = Acat @ Wcat^T
    gemm_main_kernel<<<dim3(16, 64), 256, 0, stream>>>(Acat, Wcat, out);
}

// Round 3
// 282.411 us; speedup vs baseline: 1.3933x; 1.0563x over previous
//
#include <hip/hip_runtime.h>
#include <stdint.h>

typedef unsigned short u16;
typedef short bf16x8 __attribute__((ext_vector_type(8)));   // 8 bf16 in 4 VGPRs
typedef float f32x4 __attribute__((ext_vector_type(4)));

typedef void as1_void __attribute__((address_space(1)));
typedef void as3_void __attribute__((address_space(3)));

__device__ inline u16 f32_to_bf16(float f) {
    uint32_t u = __builtin_bit_cast(uint32_t, f);
    u += 0x7fffu + ((u >> 16) & 1u);   // RNE (finite values only)
    return (u16)(u >> 16);
}

__device__ inline void gld_lds16(const void* g, void* l) {
    // async global->LDS, 16B/lane; HW dest = wave-uniform base + lane*16
    __builtin_amdgcn_global_load_lds((as1_void*)g, (as3_void*)l, 16, 0, 0);
}

// ---------------- prep kernels ----------------

__global__ void prep_w_kernel(const float* __restrict__ v_log,
                              const float* __restrict__ theta_log,
                              float* __restrict__ wfull, int H) {
    int h = blockIdx.x * blockDim.x + threadIdx.x;
    if (h < H) {
        float mag = expf(-expf(v_log[h]));
        float ang = expf(theta_log[h]);
        wfull[h]     = mag * cosf(ang);
        wfull[h + H] = mag * sinf(ang);
    }
}

// Ccat[o][k] = Cr[o][k] (k<2048), -Ci[o][k-2048] (k>=2048); row-major [1024][4096] bf16
__global__ void pack_ccat_kernel(const float* __restrict__ Cr,
                                 const float* __restrict__ Ci,
                                 u16* __restrict__ Ccat, int total4) {
    int i = blockIdx.x * blockDim.x + threadIdx.x;
    if (i >= total4) return;
    int e = i * 4;
    int o = e >> 12;
    int k = e & 4095;
    float4 f; float s;
    if (k < 2048) { f = *(const float4*)(Cr + (size_t)o * 2048 + k);          s =  1.f; }
    else          { f = *(const float4*)(Ci + (size_t)o * 2048 + (k - 2048)); s = -1.f; }
    ushort4 u;
    u.x = f32_to_bf16(s * f.x); u.y = f32_to_bf16(s * f.y);
    u.z = f32_to_bf16(s * f.z); u.w = f32_to_bf16(s * f.w);
    ((ushort4*)Ccat)[i] = u;
}

// Bcat[c][colOff + r] = bf16(src[r][c]) for src in {Br, Bi} (z-dim selects); 32x32 LDS transpose
__global__ void transpose_cast_kernel(const float* __restrict__ Br,
                                      const float* __restrict__ Bi,
                                      u16* __restrict__ Bcat) {
    __shared__ float t[32][33];
    const float* src = blockIdx.z ? Bi : Br;
    int colOff = blockIdx.z ? 2048 : 0;
    int c0 = blockIdx.x * 32, r0 = blockIdx.y * 32;
    int tx = threadIdx.x, ty = threadIdx.y;   // 32 x 8
#pragma unroll
    for (int j = 0; j < 4; j++)
        t[ty + j * 8][tx] = src[(size_t)(r0 + ty + j * 8) * 1024 + c0 + tx];
    __syncthreads();
#pragma unroll
    for (int j = 0; j < 4; j++)
        Bcat[(size_t)(c0 + ty + j * 8) * 4096 + colOff + r0 + tx] =
            f32_to_bf16(t[tx][ty + j * 8]);
}

// contiguous f32 -> bf16 copy-cast
__global__ void cast_f32_bf16_kernel(const float* __restrict__ src,
                                     u16* __restrict__ dst, int n4) {
    int i = blockIdx.x * blockDim.x + threadIdx.x;
    if (i < n4) {
        float4 f = ((const float4*)src)[i];
        ushort4 o;
        o.x = f32_to_bf16(f.x); o.y = f32_to_bf16(f.y);
        o.z = f32_to_bf16(f.z); o.w = f32_to_bf16(f.w);
        ((ushort4*)dst)[i] = o;
    }
}

// merged: [region A] Wmain[o][c] = bf16(sum_z partials[z][o][c])   (1024x1024)
//         [region B] Cwbf[o][h]  = bf16(Cr[o][h]*wr[h] - Ci[o][h]*wi[h])  (1024x2048)
__global__ void reduce_cw_kernel(const float* __restrict__ partials,
                                 const float* __restrict__ Cr, const float* __restrict__ Ci,
                                 const float* __restrict__ wfull,
                                 u16* __restrict__ Wmain, u16* __restrict__ Cwbf) {
    const int n4_red = 1024 * 1024 / 4;          // 262144
    const int n4_cw  = 1024 * 2048 / 4;          // 524288
    int i = blockIdx.x * blockDim.x + threadIdx.x;
    if (i < n4_red) {
        int e = i * 4;
        float4 s = *(const float4*)(partials + e);
#pragma unroll
        for (int z = 1; z < 4; z++) {
            float4 p = *(const float4*)(partials + ((size_t)z << 20) + e);
            s.x += p.x; s.y += p.y; s.z += p.z; s.w += p.w;
        }
        ushort4 u;
        u.x = f32_to_bf16(s.x); u.y = f32_to_bf16(s.y);
        u.z = f32_to_bf16(s.z); u.w = f32_to_bf16(s.w);
        ((ushort4*)Wmain)[i] = u;
    } else if (i < n4_red + n4_cw) {
        int j = i - n4_red;
        int e = j * 4;
        int o = e >> 11;
        int h = e & 2047;
        float4 cr = *(const float4*)(Cr + (size_t)o * 2048 + h);
        float4 ci = *(const float4*)(Ci + (size_t)o * 2048 + h);
        float4 wr = *(const float4*)(wfull + h);
        float4 wi = *(const float4*)(wfull + 2048 + h);
        ushort4 u;
        u.x = f32_to_bf16(cr.x * wr.x - ci.x * wi.x);
        u.y = f32_to_bf16(cr.y * wr.y - ci.y * wi.y);
        u.z = f32_to_bf16(cr.z * wr.z - ci.z * wi.z);
        u.w = f32_to_bf16(cr.w * wr.w - ci.w * wi.w);
        ((ushort4*)Cwbf)[j] = u;
    }
}

// ---------------- weight GEMM: split-K=4, 128x128 tile ----------------
// partials[bz][m][n] = sum_{k in 1024-chunk bz} Ccat[m][k] * Bcat[n][k], K=4096

__global__ __launch_bounds__(256)
void gemm_splitk_kernel(const u16* __restrict__ A, const u16* __restrict__ B,
                        float* __restrict__ partials)
{
    __shared__ __align__(16) u16 ldsA[128 * 32];
    __shared__ __align__(16) u16 ldsB[128 * 32];
    const int K = 4096;

    const int tid = threadIdx.x, wid = tid >> 6, lane = tid & 63;
    const int quad = lane >> 4, l16 = lane & 15;
    const int wm = wid >> 1, wn = wid & 1;
    const int bm = blockIdx.y, bn = blockIdx.x, bz = blockIdx.z;
    const int kb = bz * 1024;

    const int c0 = wid * 128 + lane, c1 = c0 + 64;
    const int r0 = c0 >> 2, o0 = (c0 & 3) * 8;
    const int r1 = c1 >> 2, o1 = (c1 & 3) * 8;

    const u16* gA0 = A + (size_t)(bm * 128 + r0) * K + o0 + kb;
    const u16* gA1 = A + (size_t)(bm * 128 + r1) * K + o1 + kb;
    const u16* gB0 = B + (size_t)(bn * 128 + r0) * K + o0 + kb;
    const u16* gB1 = B + (size_t)(bn * 128 + r1) * K + o1 + kb;
    u16* lA0 = ldsA + c0 * 8; u16* lA1 = ldsA + c1 * 8;
    u16* lB0 = ldsB + c0 * 8; u16* lB1 = ldsB + c1 * 8;

    const f32x4 fz = {0.f, 0.f, 0.f, 0.f};
    f32x4 acc[4][4];
#pragma unroll
    for (int i = 0; i < 4; i++)
#pragma unroll
        for (int j = 0; j < 4; j++) acc[i][j] = fz;

    for (int k0 = 0; k0 < 1024; k0 += 32) {
        __syncthreads();
        gld_lds16(gA0 + k0, lA0);
        gld_lds16(gA1 + k0, lA1);
        gld_lds16(gB0 + k0, lB0);
        gld_lds16(gB1 + k0, lB1);
        __syncthreads();
        bf16x8 af[4], bfr[4];
#pragma unroll
        for (int i = 0; i < 4; i++)
            af[i] = *(const bf16x8*)(ldsA + (wm * 64 + i * 16 + l16) * 32 + quad * 8);
#pragma unroll
        for (int j = 0; j < 4; j++)
            bfr[j] = *(const bf16x8*)(ldsB + (wn * 64 + j * 16 + l16) * 32 + quad * 8);
#pragma unroll
        for (int i = 0; i < 4; i++)
#pragma unroll
            for (int j = 0; j < 4; j++)
                acc[i][j] = __builtin_amdgcn_mfma_f32_16x16x32_bf16(af[i], bfr[j], acc[i][j], 0, 0, 0);
    }

    float* P = partials + ((size_t)bz << 20);
    const int gm = bm * 128 + wm * 64, gn = bn * 128 + wn * 64;
#pragma unroll
    for (int i = 0; i < 4; i++)
#pragma unroll
        for (int j = 0; j < 4; j++) {
            int col = gn + j * 16 + l16;
#pragma unroll
            for (int r = 0; r < 4; r++)
                P[(size_t)(gm + i * 16 + quad * 4 + r) * 1024 + col] = acc[i][j][r];
        }
}

// ---------------- main GEMM ----------------
// out[8192,1024] = [x_bf | hp_bf] @ [Wmain | Cwbf]^T, two K-phases, m97 128x128 tile.

__global__ __launch_bounds__(256)
void gemm_main_kernel(const u16* __restrict__ Axb, const u16* __restrict__ Ahb,
                      const u16* __restrict__ Bw,  const u16* __restrict__ Bcw,
                      float* __restrict__ out)
{
    __shared__ __align__(16) u16 ldsA[128 * 32];
    __shared__ __align__(16) u16 ldsB[128 * 32];

    const int tid = threadIdx.x, wid = tid >> 6, lane = tid & 63;
    const int quad = lane >> 4, l16 = lane & 15;
    const int wm = wid >> 1, wn = wid & 1;
    const int bm = blockIdx.y, bn = blockIdx.x;

    const int c0 = wid * 128 + lane, c1 = c0 + 64;
    const int r0 = c0 >> 2, o0 = (c0 & 3) * 8;
    const int r1 = c1 >> 2, o1 = (c1 & 3) * 8;
    u16* lA0 = ldsA + c0 * 8; u16* lA1 = ldsA + c1 * 8;
    u16* lB0 = ldsB + c0 * 8; u16* lB1 = ldsB + c1 * 8;

    const f32x4 fz = {0.f, 0.f, 0.f, 0.f};
    f32x4 acc[4][4];
#pragma unroll
    for (int i = 0; i < 4; i++)
#pragma unroll
        for (int j = 0; j < 4; j++) acc[i][j] = fz;

#pragma unroll 1
    for (int phase = 0; phase < 2; phase++) {
        const u16* Ap = phase ? Ahb : Axb;
        const u16* Bp = phase ? Bcw : Bw;
        const int KS = phase ? 2048 : 1024;
        const u16* gA0 = Ap + (size_t)(bm * 128 + r0) * KS + o0;
        const u16* gA1 = Ap + (size_t)(bm * 128 + r1) * KS + o1;
        const u16* gB0 = Bp + (size_t)(bn * 128 + r0) * KS + o0;
        const u16* gB1 = Bp + (size_t)(bn * 128 + r1) * KS + o1;
        for (int k0 = 0; k0 < KS; k0 += 32) {
            __syncthreads();
            gld_lds16(gA0 + k0, lA0);
            gld_lds16(gA1 + k0, lA1);
            gld_lds16(gB0 + k0, lB0);
            gld_lds16(gB1 + k0, lB1);
            __syncthreads();
            bf16x8 af[4], bfr[4];
#pragma unroll
            for (int i = 0; i < 4; i++)
                af[i] = *(const bf16x8*)(ldsA + (wm * 64 + i * 16 + l16) * 32 + quad * 8);
#pragma unroll
            for (int j = 0; j < 4; j++)
                bfr[j] = *(const bf16x8*)(ldsB + (wn * 64 + j * 16 + l16) * 32 + quad * 8);
#pragma unroll
            for (int i = 0; i < 4; i++)
#pragma unroll
                for (int j = 0; j < 4; j++)
                    acc[i][j] = __builtin_amdgcn_mfma_f32_16x16x32_bf16(af[i], bfr[j], acc[i][j], 0, 0, 0);
        }
    }

    const int gm = bm * 128 + wm * 64, gn = bn * 128 + wn * 64;
#pragma unroll
    for (int i = 0; i < 4; i++)
#pragma unroll
        for (int j = 0; j < 4; j++) {
            int col = gn + j * 16 + l16;
#pragma unroll
            for (int r = 0; r < 4; r++)
                out[(size_t)(gm + i * 16 + quad * 4 + r) * 1024 + col] = acc[i][j][r];
        }
}

// ---------------- launch ----------------

extern "C" void kernel_launch(void* const* d_in, const int* in_sizes, int n_in,
                              void* d_out, int out_size, void* d_ws, size_t ws_size,
                              hipStream_t stream)
{
    const float* x      = (const float*)d_in[0];
    const float* h_prev = (const float*)d_in[1];
    const float* Br     = (const float*)d_in[2];
    const float* Bi     = (const float*)d_in[3];
    const float* Cr     = (const float*)d_in[4];
    const float* Ci     = (const float*)d_in[5];
    const float* v_log  = (const float*)d_in[6];
    const float* th_log = (const float*)d_in[7];
    float* out = (float*)d_out;

    const size_t MB = 1024 * 1024;
    // region0 (48 MB): prep phase {Ccat 8 | Bcat 8 | partials 16 | pad}, then {x_bf 16 | hp_bf 32}
    size_t need = 48 * MB + 2 * MB + 4 * MB + 4096 * 4;
    if (ws_size < need) return;

    char* ws = (char*)d_ws;
    u16*   Ccat     = (u16*)ws;                   // [1024,4096] bf16
    u16*   Bcat     = (u16*)(ws + 8 * MB);        // [1024,4096] bf16 = [BrT|BiT]
    float* partials = (float*)(ws + 16 * MB);     // [4][1024][1024] f32
    u16*   x_bf     = (u16*)ws;                   // [8192,1024] bf16 (aliases Ccat/Bcat)
    u16*   hp_bf    = (u16*)(ws + 16 * MB);       // [8192,2048] bf16 (aliases partials)
    u16*   Wmain    = (u16*)(ws + 48 * MB);       // [1024,1024] bf16
    u16*   Cwbf     = (u16*)(ws + 50 * MB);       // [1024,2048] bf16
    float* wfull    = (float*)(ws + 54 * MB);     // [4096] f32

    // 1) diagonal weights
    prep_w_kernel<<<8, 256, 0, stream>>>(v_log, th_log, wfull, 2048);
    // 2) Ccat = [Cr | -Ci]
    pack_ccat_kernel<<<4096, 256, 0, stream>>>(Cr, Ci, Ccat, 1024 * 4096 / 4);
    // 3) Bcat = [Br^T | Bi^T]
    transpose_cast_kernel<<<dim3(32, 64, 2), dim3(32, 8), 0, stream>>>(Br, Bi, Bcat);
    // 4) partials = Ccat @ Bcat^T (split-K=4)
    gemm_splitk_kernel<<<dim3(8, 8, 4), 256, 0, stream>>>(Ccat, Bcat, partials);
    // 5) Wmain = bf16(sum partials); Cwbf = bf16(Cr*wr - Ci*wi)
    reduce_cw_kernel<<<3072, 256, 0, stream>>>(partials, Cr, Ci, wfull, Wmain, Cwbf);
    // 6) contiguous copy-casts (overwrite prep buffers — consumed above)
    cast_f32_bf16_kernel<<<8192, 256, 0, stream>>>(x, x_bf, 8192 * 1024 / 4);
    cast_f32_bf16_kernel<<<16384, 256, 0, stream>>>(h_prev, hp_bf, 8192 * 2048 / 4);
    // 7) out = [x_bf | hp_bf] @ [Wmain | Cwbf]^T
    gemm_main_kernel<<<dim3(8, 64), 256, 0, stream>>>(x_bf, hp_bf, Wmain, Cwbf, out);
}

// Round 4
// 250.922 us; speedup vs baseline: 1.5682x; 1.1255x over previous
//
#include <hip/hip_runtime.h>
#include <stdint.h>

typedef unsigned short u16;
typedef short bf16x8 __attribute__((ext_vector_type(8)));   // 8 bf16 in 4 VGPRs
typedef float f32x4 __attribute__((ext_vector_type(4)));

typedef void as1_void __attribute__((address_space(1)));
typedef void as3_void __attribute__((address_space(3)));

__device__ inline u16 f32_to_bf16(float f) {
    uint32_t u = __builtin_bit_cast(uint32_t, f);
    u += 0x7fffu + ((u >> 16) & 1u);   // RNE (finite values only)
    return (u16)(u >> 16);
}

__device__ inline void gld_lds16(const void* g, void* l) {
    // async global->LDS, 16B/lane; HW dest = wave-uniform base + lane*16
    __builtin_amdgcn_global_load_lds((as1_void*)g, (as3_void*)l, 16, 0, 0);
}

// LDS tile layout (both GEMMs): 128 rows x 64 cols bf16, stored as 1024 chunks of
// 16B. Global (row, colchunk j) lives at chunk slot row*8 + (j ^ (row&7)).
// The XOR swizzle spreads same-column frag reads across all 32 banks (2-way max,
// free per m136) while keeping each staging issue 64 lane-contiguous slots.

// ---------------- prep kernels ----------------

__global__ void prep_w_kernel(const float* __restrict__ v_log,
                              const float* __restrict__ theta_log,
                              float* __restrict__ wfull, int H) {
    int h = blockIdx.x * blockDim.x + threadIdx.x;
    if (h < H) {
        float mag = expf(-expf(v_log[h]));
        float ang = expf(theta_log[h]);
        wfull[h]     = mag * cosf(ang);
        wfull[h + H] = mag * sinf(ang);
    }
}

// Ccat[o][k] = Cr[o][k] (k<2048), -Ci[o][k-2048]; row-major [1024][4096] bf16
__global__ void pack_ccat_kernel(const float* __restrict__ Cr,
                                 const float* __restrict__ Ci,
                                 u16* __restrict__ Ccat, int total4) {
    int i = blockIdx.x * blockDim.x + threadIdx.x;
    if (i >= total4) return;
    int e = i * 4;
    int o = e >> 12;
    int k = e & 4095;
    float4 f; float s;
    if (k < 2048) { f = *(const float4*)(Cr + (size_t)o * 2048 + k);          s =  1.f; }
    else          { f = *(const float4*)(Ci + (size_t)o * 2048 + (k - 2048)); s = -1.f; }
    ushort4 u;
    u.x = f32_to_bf16(s * f.x); u.y = f32_to_bf16(s * f.y);
    u.z = f32_to_bf16(s * f.z); u.w = f32_to_bf16(s * f.w);
    ((ushort4*)Ccat)[i] = u;
}

// Bcat[c][colOff + r] = bf16(src[r][c]); 32x32 LDS tile transpose, z selects Br/Bi
__global__ void transpose_cast_kernel(const float* __restrict__ Br,
                                      const float* __restrict__ Bi,
                                      u16* __restrict__ Bcat) {
    __shared__ float t[32][33];
    const float* src = blockIdx.z ? Bi : Br;
    int colOff = blockIdx.z ? 2048 : 0;
    int c0 = blockIdx.x * 32, r0 = blockIdx.y * 32;
    int tx = threadIdx.x, ty = threadIdx.y;   // 32 x 8
#pragma unroll
    for (int j = 0; j < 4; j++)
        t[ty + j * 8][tx] = src[(size_t)(r0 + ty + j * 8) * 1024 + c0 + tx];
    __syncthreads();
#pragma unroll
    for (int j = 0; j < 4; j++)
        Bcat[(size_t)(c0 + ty + j * 8) * 4096 + colOff + r0 + tx] =
            f32_to_bf16(t[tx][ty + j * 8]);
}

// merged cast: dst[0..16MB) = bf16(x), dst[16MB..48MB) = bf16(h_prev) (adjacent)
__global__ void cast_both_kernel(const float* __restrict__ x,
                                 const float* __restrict__ h_prev,
                                 u16* __restrict__ dst) {
    const int n4x = 8192 * 1024 / 4;     // 2097152
    int i = blockIdx.x * blockDim.x + threadIdx.x;
    float4 f = (i < n4x) ? ((const float4*)x)[i] : ((const float4*)h_prev)[i - n4x];
    ushort4 o;
    o.x = f32_to_bf16(f.x); o.y = f32_to_bf16(f.y);
    o.z = f32_to_bf16(f.z); o.w = f32_to_bf16(f.w);
    ((ushort4*)dst)[i] = o;
}

// [region A] Wmain[o][c] = bf16(sum_z partials[z][o][c]); [region B] Cwbf = bf16(Cr*wr - Ci*wi)
__global__ void reduce_cw_kernel(const float* __restrict__ partials,
                                 const float* __restrict__ Cr, const float* __restrict__ Ci,
                                 const float* __restrict__ wfull,
                                 u16* __restrict__ Wmain, u16* __restrict__ Cwbf) {
    const int n4_red = 1024 * 1024 / 4;
    const int n4_cw  = 1024 * 2048 / 4;
    int i = blockIdx.x * blockDim.x + threadIdx.x;
    if (i < n4_red) {
        int e = i * 4;
        float4 s = *(const float4*)(partials + e);
#pragma unroll
        for (int z = 1; z < 8; z++) {
            float4 p = *(const float4*)(partials + ((size_t)z << 20) + e);
            s.x += p.x; s.y += p.y; s.z += p.z; s.w += p.w;
        }
        ushort4 u;
        u.x = f32_to_bf16(s.x); u.y = f32_to_bf16(s.y);
        u.z = f32_to_bf16(s.z); u.w = f32_to_bf16(s.w);
        ((ushort4*)Wmain)[i] = u;
    } else if (i < n4_red + n4_cw) {
        int j = i - n4_red;
        int e = j * 4;
        int o = e >> 11;
        int h = e & 2047;
        float4 cr = *(const float4*)(Cr + (size_t)o * 2048 + h);
        float4 ci = *(const float4*)(Ci + (size_t)o * 2048 + h);
        float4 wr = *(const float4*)(wfull + h);
        float4 wi = *(const float4*)(wfull + 2048 + h);
        ushort4 u;
        u.x = f32_to_bf16(cr.x * wr.x - ci.x * wi.x);
        u.y = f32_to_bf16(cr.y * wr.y - ci.y * wi.y);
        u.z = f32_to_bf16(cr.z * wr.z - ci.z * wi.z);
        u.w = f32_to_bf16(cr.w * wr.w - ci.w * wi.w);
        ((ushort4*)Cwbf)[j] = u;
    }
}

// ---------------- weight GEMM: split-K=8, 128x128 tile, BK=64 ----------------
// partials[bz][m][n] = sum_{k in 512-chunk bz} Ccat[m][k] * Bcat[n][k], K=4096

__global__ __launch_bounds__(256)
void gemm_splitk_kernel(const u16* __restrict__ A, const u16* __restrict__ B,
                        float* __restrict__ partials)
{
    __shared__ __align__(16) u16 ldsA[128 * 64];
    __shared__ __align__(16) u16 ldsB[128 * 64];
    const int K = 4096;

    const int tid = threadIdx.x, wid = tid >> 6, lane = tid & 63;
    const int quad = lane >> 4, l16 = lane & 15;
    const int wm = wid >> 1, wn = wid & 1;
    const int bm = blockIdx.y, bn = blockIdx.x, bz = blockIdx.z;
    const int kb = bz * 512;

    const u16* gA[4]; const u16* gB[4];
    u16 *lA[4], *lB[4];
#pragma unroll
    for (int t = 0; t < 4; t++) {
        int s = wid * 256 + t * 64 + lane;
        int sr = s >> 3;
        int sj = (s & 7) ^ (sr & 7);
        lA[t] = ldsA + s * 8;
        lB[t] = ldsB + s * 8;
        gA[t] = A + (size_t)(bm * 128 + sr) * K + sj * 8 + kb;
        gB[t] = B + (size_t)(bn * 128 + sr) * K + sj * 8 + kb;
    }

    const f32x4 fz = {0.f, 0.f, 0.f, 0.f};
    f32x4 acc[4][4];
#pragma unroll
    for (int i = 0; i < 4; i++)
#pragma unroll
        for (int j = 0; j < 4; j++) acc[i][j] = fz;

    for (int k0 = 0; k0 < 512; k0 += 64) {
        __syncthreads();
#pragma unroll
        for (int t = 0; t < 4; t++) {
            gld_lds16(gA[t] + k0, lA[t]);
            gld_lds16(gB[t] + k0, lB[t]);
        }
        __syncthreads();
#pragma unroll
        for (int ks = 0; ks < 2; ks++) {
            bf16x8 af[4], bfr[4];
#pragma unroll
            for (int i = 0; i < 4; i++) {
                int r = wm * 64 + i * 16 + l16;
                af[i] = *(const bf16x8*)(ldsA + (r * 8 + ((ks * 4 + quad) ^ (r & 7))) * 8);
            }
#pragma unroll
            for (int j = 0; j < 4; j++) {
                int r = wn * 64 + j * 16 + l16;
                bfr[j] = *(const bf16x8*)(ldsB + (r * 8 + ((ks * 4 + quad) ^ (r & 7))) * 8);
            }
#pragma unroll
            for (int i = 0; i < 4; i++)
#pragma unroll
                for (int j = 0; j < 4; j++)
                    acc[i][j] = __builtin_amdgcn_mfma_f32_16x16x32_bf16(af[i], bfr[j], acc[i][j], 0, 0, 0);
        }
    }

    float* P = partials + ((size_t)bz << 20);
    const int gm = bm * 128 + wm * 64, gn = bn * 128 + wn * 64;
#pragma unroll
    for (int i = 0; i < 4; i++)
#pragma unroll
        for (int j = 0; j < 4; j++) {
            int col = gn + j * 16 + l16;
#pragma unroll
            for (int r = 0; r < 4; r++)
                P[(size_t)(gm + i * 16 + quad * 4 + r) * 1024 + col] = acc[i][j][r];
        }
}

// ---------------- main GEMM ----------------
// out[8192,1024] = [x_bf | hp_bf] @ [Wmain | Cwbf]^T, two K-phases, 128x128 tile, BK=64.
// 1D grid of 512; bm = id&63 so the 8 blocks sharing an A-tile share id%8 (same XCD).

__global__ __launch_bounds__(256)
void gemm_main_kernel(const u16* __restrict__ Axb, const u16* __restrict__ Ahb,
                      const u16* __restrict__ Bw,  const u16* __restrict__ Bcw,
                      float* __restrict__ out)
{
    __shared__ __align__(16) u16 ldsA[128 * 64];
    __shared__ __align__(16) u16 ldsB[128 * 64];

    const int tid = threadIdx.x, wid = tid >> 6, lane = tid & 63;
    const int quad = lane >> 4, l16 = lane & 15;
    const int wm = wid >> 1, wn = wid & 1;
    const int id = blockIdx.x;
    const int bm = id & 63, bn = id >> 6;

    int srow[4], sj[4];
    u16 *lA[4], *lB[4];
#pragma unroll
    for (int t = 0; t < 4; t++) {
        int s = wid * 256 + t * 64 + lane;
        srow[t] = s >> 3;
        sj[t] = (s & 7) ^ (srow[t] & 7);
        lA[t] = ldsA + s * 8;
        lB[t] = ldsB + s * 8;
    }

    const f32x4 fz = {0.f, 0.f, 0.f, 0.f};
    f32x4 acc[4][4];
#pragma unroll
    for (int i = 0; i < 4; i++)
#pragma unroll
        for (int j = 0; j < 4; j++) acc[i][j] = fz;

#pragma unroll 1
    for (int phase = 0; phase < 2; phase++) {
        const u16* Ap = phase ? Ahb : Axb;
        const u16* Bp = phase ? Bcw : Bw;
        const int KS = phase ? 2048 : 1024;
        const u16* gA[4]; const u16* gB[4];
#pragma unroll
        for (int t = 0; t < 4; t++) {
            gA[t] = Ap + (size_t)(bm * 128 + srow[t]) * KS + sj[t] * 8;
            gB[t] = Bp + (size_t)(bn * 128 + srow[t]) * KS + sj[t] * 8;
        }
        for (int k0 = 0; k0 < KS; k0 += 64) {
            __syncthreads();
#pragma unroll
            for (int t = 0; t < 4; t++) {
                gld_lds16(gA[t] + k0, lA[t]);
                gld_lds16(gB[t] + k0, lB[t]);
            }
            __syncthreads();
#pragma unroll
            for (int ks = 0; ks < 2; ks++) {
                bf16x8 af[4], bfr[4];
#pragma unroll
                for (int i = 0; i < 4; i++) {
                    int r = wm * 64 + i * 16 + l16;
                    af[i] = *(const bf16x8*)(ldsA + (r * 8 + ((ks * 4 + quad) ^ (r & 7))) * 8);
                }
#pragma unroll
                for (int j = 0; j < 4; j++) {
                    int r = wn * 64 + j * 16 + l16;
                    bfr[j] = *(const bf16x8*)(ldsB + (r * 8 + ((ks * 4 + quad) ^ (r & 7))) * 8);
                }
#pragma unroll
                for (int i = 0; i < 4; i++)
#pragma unroll
                    for (int j = 0; j < 4; j++)
                        acc[i][j] = __builtin_amdgcn_mfma_f32_16x16x32_bf16(af[i], bfr[j], acc[i][j], 0, 0, 0);
            }
        }
    }

    const int gm = bm * 128 + wm * 64, gn = bn * 128 + wn * 64;
#pragma unroll
    for (int i = 0; i < 4; i++)
#pragma unroll
        for (int j = 0; j < 4; j++) {
            int col = gn + j * 16 + l16;
#pragma unroll
            for (int r = 0; r < 4; r++)
                out[(size_t)(gm + i * 16 + quad * 4 + r) * 1024 + col] = acc[i][j][r];
        }
}

// ---------------- launch ----------------

extern "C" void kernel_launch(void* const* d_in, const int* in_sizes, int n_in,
                              void* d_out, int out_size, void* d_ws, size_t ws_size,
                              hipStream_t stream)
{
    const float* x      = (const float*)d_in[0];
    const float* h_prev = (const float*)d_in[1];
    const float* Br     = (const float*)d_in[2];
    const float* Bi     = (const float*)d_in[3];
    const float* Cr     = (const float*)d_in[4];
    const float* Ci     = (const float*)d_in[5];
    const float* v_log  = (const float*)d_in[6];
    const float* th_log = (const float*)d_in[7];
    float* out = (float*)d_out;

    const size_t MB = 1024 * 1024;
    // region0 (48 MB): prep phase {Ccat 8 | Bcat 8 | partials 32}, then {x_bf 16 | hp_bf 32}
    size_t need = 54 * MB + 4096 * 4;
    if (ws_size < need) return;

    char* ws = (char*)d_ws;
    u16*   Ccat     = (u16*)ws;                   // [1024,4096] bf16
    u16*   Bcat     = (u16*)(ws + 8 * MB);        // [1024,4096] bf16 = [BrT|BiT]
    float* partials = (float*)(ws + 16 * MB);     // [8][1024][1024] f32
    u16*   x_bf     = (u16*)ws;                   // [8192,1024] bf16 (aliases Ccat/Bcat)
    u16*   hp_bf    = (u16*)(ws + 16 * MB);       // [8192,2048] bf16 (aliases partials)
    u16*   Wmain    = (u16*)(ws + 48 * MB);       // [1024,1024] bf16
    u16*   Cwbf     = (u16*)(ws + 50 * MB);       // [1024,2048] bf16
    float* wfull    = (float*)(ws + 54 * MB);     // [4096] f32

    // 1) diagonal weights
    prep_w_kernel<<<8, 256, 0, stream>>>(v_log, th_log, wfull, 2048);
    // 2) Ccat = [Cr | -Ci]
    pack_ccat_kernel<<<4096, 256, 0, stream>>>(Cr, Ci, Ccat, 1024 * 4096 / 4);
    // 3) Bcat = [Br^T | Bi^T]
    transpose_cast_kernel<<<dim3(32, 64, 2), dim3(32, 8), 0, stream>>>(Br, Bi, Bcat);
    // 4) partials = Ccat @ Bcat^T (split-K=8, 512 blocks)
    gemm_splitk_kernel<<<dim3(8, 8, 8), 256, 0, stream>>>(Ccat, Bcat, partials);
    // 5) Wmain = bf16(sum partials); Cwbf = bf16(Cr*wr - Ci*wi)
    reduce_cw_kernel<<<3072, 256, 0, stream>>>(partials, Cr, Ci, wfull, Wmain, Cwbf);
    // 6) single cast kernel: [x | h_prev] -> bf16 (overwrites prep buffers — consumed)
    cast_both_kernel<<<24576, 256, 0, stream>>>(x, h_prev, x_bf);
    // 7) out = [x_bf | hp_bf] @ [Wmain | Cwbf]^T
    gemm_main_kernel<<<512, 256, 0, stream>>>(x_bf, hp_bf, Wmain, Cwbf, out);
}